// Round 1
// 193.844 us; speedup vs baseline: 1.0281x; 1.0281x over previous
//
#include <hip/hip_runtime.h>

#define K_ITERS 50

// LDS float layout (total 14178 floats = 56712 B):
//  [0, 4624)      : setup scratch (h_w 2700 | r_w 1350 | h_b 150) -> X0 (68x68 ring-2) -> vA (66x68 ring-1)
//  [4624, 9248)   : X1 (68x68 ring-2)  -> reused as vB (66x68 ring-1)
//  [9248, 13736)  : R  (66x68 ring-1)
//  [13736, 14178) : weights: w2(162) rhb(+162) qw(+171,180) qb(+351,10) fcw(+361,80) rb(+441)
#define SR_OFF 9248
#define SW_OFF 13736
#define LDS_TOT 14178

__device__ __forceinline__ void vi_step(const float* __restrict__ cur, float* __restrict__ nxt,
                                        int row, int col0,
                                        const float (&qr)[10][8], const float (&qwv)[10][9]) {
    float nb[3][12];
#pragma unroll
    for (int dy = 0; dy < 3; ++dy) {
#pragma unroll
        for (int j = 0; j < 3; ++j) {
            float4 v = *(const float4*)&cur[(row + dy) * 68 + col0 + 4 * j];
            nb[dy][4 * j + 0] = v.x; nb[dy][4 * j + 1] = v.y;
            nb[dy][4 * j + 2] = v.z; nb[dy][4 * j + 3] = v.w;
        }
    }
    float vmax[8];
#pragma unroll
    for (int c = 0; c < 10; ++c) {
#pragma unroll
        for (int p = 0; p < 8; ++p) {
            float acc = qr[c][p];
#pragma unroll
            for (int ky = 0; ky < 3; ++ky)
#pragma unroll
                for (int kx = 0; kx < 3; ++kx)
                    acc = fmaf(qwv[c][ky * 3 + kx], nb[ky][p + kx], acc);
            vmax[p] = (c == 0) ? acc : fmaxf(vmax[p], acc);
        }
    }
#pragma unroll
    for (int p = 0; p < 8; ++p)
        nxt[(row + 1) * 68 + col0 + 1 + p] = vmax[p];
}

// 512 threads = 8 waves = exactly 2 waves/SIMD with 1 block/CU -> ask for 2 waves/EU
// so the register allocator gets the full 256-VGPR budget (qr[80]+qwv[90]+nb[36]+vmax[8]
// must be register-resident; at the old 124-VGPR cap they spilled to scratch:
// WRITE_SIZE was 20.5 MB/dispatch vs 4 KB of true output).
__launch_bounds__(512, 2)
__global__ void vin_main(const float* __restrict__ x,
                         const int* __restrict__ pos_x, const int* __restrict__ pos_y,
                         const float* __restrict__ h_w, const float* __restrict__ h_b,
                         const float* __restrict__ r_w, const float* __restrict__ r_b,
                         const float* __restrict__ q_w, const float* __restrict__ q_b,
                         const float* __restrict__ fc_w, float* __restrict__ out) {
    __shared__ __align__(16) float S[LDS_TOT];
    const int tid = threadIdx.x;
    const int b = blockIdx.x;
    const int row = tid >> 3;          // 0..63
    const int col0 = (tid & 7) << 3;   // 0,8,..,56
    float* SW = S + SW_OFF;

    // phase A: stage raw weights into scratch (region later zeroed for X0/X1),
    //          and loop weights into SW[171..442)
    for (int i = tid; i < 2700; i += 512) S[i] = h_w[i];
    for (int i = tid; i < 1350; i += 512) S[2700 + i] = r_w[i];
    if (tid < 150) S[4050 + tid] = h_b[tid];
    for (int i = tid; i < 180; i += 512) SW[171 + i] = q_w[i];
    if (tid < 10) SW[351 + tid] = q_b[tid];
    for (int i = tid; i < 80; i += 512) SW[361 + i] = fc_w[i];
    if (tid == 0) SW[441] = r_b[0];
    __syncthreads();

    // phase B: composite 2-stage conv weights w2[2][9][9] + rhb[9] (fmaf order
    // identical to the old vin_setup kernel -> bitwise-identical results)
    if (tid < 162) {
        int i = tid / 81, rem = tid % 81, dq = rem / 9, ds = rem % 9;
        const float* rw = S + 2700;
        float s = 0.f;
        for (int m = 0; m < 150; ++m)
            s = fmaf(rw[m * 9 + dq], S[(m * 2 + i) * 9 + ds], s);
        SW[tid] = s;
    } else if (tid < 171) {
        int dq = tid - 162;
        const float* rw = S + 2700;
        const float* hb = S + 4050;
        float s = 0.f;
        for (int m = 0; m < 150; ++m)
            s = fmaf(rw[m * 9 + dq], hb[m], s);
        SW[tid] = s;
    }
    __syncthreads();

    // phase 0: zero X0/X1/R regions (13736 = 4*3434 floats)
    float4 z4 = make_float4(0.f, 0.f, 0.f, 0.f);
    for (int i = tid; i < 3434; i += 512) ((float4*)S)[i] = z4;
    __syncthreads();

    // phase 1: stage x[b] into X0/X1 interior (ring-2 stays zero)
    {
        const float4* xg = (const float4*)(x + (size_t)b * 8192);
        for (int i = tid; i < 2048; i += 512) {
            float4 v = xg[i];
            int ch = i >> 10, rem = i & 1023;
            int y = rem >> 4, xc = (rem & 15) << 2;
            float* dst = S + ch * 4624 + (y + 2) * 68 + xc + 2;
            dst[0] = v.x; dst[1] = v.y; dst[2] = v.z; dst[3] = v.w;
        }
    }
    __syncthreads();

    // phase 2: r = composite 2-stage conv via w2/rhb, exact border clipping on q
    {
        float xb0[5][12], xb1[5][12];
        const float* X0 = S;
        const float* X1 = S + 4624;
#pragma unroll
        for (int dy = 0; dy < 5; ++dy) {
#pragma unroll
            for (int j = 0; j < 3; ++j) {
                float4 a = *(const float4*)&X0[(row + dy) * 68 + col0 + 4 * j];
                xb0[dy][4 * j + 0] = a.x; xb0[dy][4 * j + 1] = a.y;
                xb0[dy][4 * j + 2] = a.z; xb0[dy][4 * j + 3] = a.w;
                float4 c = *(const float4*)&X1[(row + dy) * 68 + col0 + 4 * j];
                xb1[dy][4 * j + 0] = c.x; xb1[dy][4 * j + 1] = c.y;
                xb1[dy][4 * j + 2] = c.z; xb1[dy][4 * j + 3] = c.w;
            }
        }
        float racc[8];
        float rbv = SW[441];
#pragma unroll
        for (int p = 0; p < 8; ++p) racc[p] = rbv;
#pragma unroll
        for (int dqy = 0; dqy < 3; ++dqy) {
            bool rowok = (row + dqy >= 1) && (row + dqy <= 64);
#pragma unroll
            for (int dqx = 0; dqx < 3; ++dqx) {
                int dq = dqy * 3 + dqx;
                float rh = SW[162 + dq];
                float w20[9], w21[9];
#pragma unroll
                for (int ds = 0; ds < 9; ++ds) {
                    w20[ds] = SW[dq * 9 + ds];
                    w21[ds] = SW[81 + dq * 9 + ds];
                }
#pragma unroll
                for (int p = 0; p < 8; ++p) {
                    float t = rh;
#pragma unroll
                    for (int dsy = 0; dsy < 3; ++dsy)
#pragma unroll
                        for (int dsx = 0; dsx < 3; ++dsx) {
                            int ds = dsy * 3 + dsx;
                            t = fmaf(w20[ds], xb0[dqy + dsy][p + dqx + dsx], t);
                            t = fmaf(w21[ds], xb1[dqy + dsy][p + dqx + dsx], t);
                        }
                    int qx = col0 + p + dqx - 1;
                    bool ok = rowok && (qx >= 0) && (qx < 64);
                    racc[p] += ok ? t : 0.f;
                }
            }
        }
        float* SR = S + SR_OFF;
#pragma unroll
        for (int p = 0; p < 8; ++p)
            SR[(row + 1) * 68 + col0 + 1 + p] = racc[p];
    }
    __syncthreads();

    // phase 3: qr = conv(r, q_w[:,0]) + q_b into registers; load loop weights; re-zero v buffers
    float qr[10][8];
    float qwv[10][9];
    {
        float rnb[3][12];
        const float* SR = S + SR_OFF;
#pragma unroll
        for (int dy = 0; dy < 3; ++dy) {
#pragma unroll
            for (int j = 0; j < 3; ++j) {
                float4 v = *(const float4*)&SR[(row + dy) * 68 + col0 + 4 * j];
                rnb[dy][4 * j + 0] = v.x; rnb[dy][4 * j + 1] = v.y;
                rnb[dy][4 * j + 2] = v.z; rnb[dy][4 * j + 3] = v.w;
            }
        }
#pragma unroll
        for (int c = 0; c < 10; ++c) {
            float qbc = SW[351 + c];
            float w[9];
#pragma unroll
            for (int j = 0; j < 9; ++j) w[j] = SW[171 + c * 18 + j];
#pragma unroll
            for (int p = 0; p < 8; ++p) {
                float acc = qbc;
#pragma unroll
                for (int ky = 0; ky < 3; ++ky)
#pragma unroll
                    for (int kx = 0; kx < 3; ++kx)
                        acc = fmaf(w[ky * 3 + kx], rnb[ky][p + kx], acc);
                qr[c][p] = acc;
            }
        }
#pragma unroll
        for (int c = 0; c < 10; ++c)
#pragma unroll
            for (int j = 0; j < 9; ++j) qwv[c][j] = SW[171 + c * 18 + 9 + j];
        // re-zero vA/vB region (was X0/X1 with x data); v0 = 0, rings stay 0 forever
        for (int i = tid; i < 2312; i += 512) ((float4*)S)[i] = z4;
    }
    __syncthreads();

    // phase 4: 50 VI steps, double-buffered v in LDS (ends with result in vA)
    float* vA = S;
    float* vB = S + 4624;
#pragma unroll 1
    for (int k = 0; k < K_ITERS / 2; ++k) {
        vi_step(vA, vB, row, col0, qr, qwv);
        __syncthreads();
        vi_step(vB, vA, row, col0, qr, qwv);
        __syncthreads();
    }

    // phase 5: final q at (pos_x, pos_y) + FC, by the owning thread
    int pr = pos_x[b], pc = pos_y[b];
    if (row == pr && (pc >> 3) == (tid & 7)) {
        int p = pc & 7;
        float qf[10];
#pragma unroll
        for (int c = 0; c < 10; ++c) {
            float acc = qr[c][p];
#pragma unroll
            for (int ky = 0; ky < 3; ++ky)
#pragma unroll
                for (int kx = 0; kx < 3; ++kx)
                    acc = fmaf(qwv[c][3 * ky + kx], vA[(pr + ky) * 68 + pc + kx], acc);
            qf[c] = acc;
        }
#pragma unroll
        for (int o = 0; o < 8; ++o) {
            float s = 0.f;
#pragma unroll
            for (int c = 0; c < 10; ++c) s = fmaf(SW[361 + o * 10 + c], qf[c], s);
            out[b * 8 + o] = s;
        }
    }
}

extern "C" void kernel_launch(void* const* d_in, const int* in_sizes, int n_in,
                              void* d_out, int out_size, void* d_ws, size_t ws_size,
                              hipStream_t stream) {
    const float* x     = (const float*)d_in[0];
    const int*   pos_x = (const int*)d_in[1];
    const int*   pos_y = (const int*)d_in[2];
    const float* h_w   = (const float*)d_in[3];
    const float* h_b   = (const float*)d_in[4];
    const float* r_w   = (const float*)d_in[5];
    const float* r_b   = (const float*)d_in[6];
    const float* q_w   = (const float*)d_in[7];
    const float* q_b   = (const float*)d_in[8];
    const float* fc_w  = (const float*)d_in[9];
    float* out = (float*)d_out;

    vin_main<<<128, 512, 0, stream>>>(x, pos_x, pos_y, h_w, h_b, r_w, r_b, q_w, q_b, fc_w, out);
}

// Round 2
// 182.716 us; speedup vs baseline: 1.0907x; 1.0609x over previous
//
#include <hip/hip_runtime.h>

#define K_ITERS 50

// LDS float layout (total 14178 floats = 56712 B):
//  [0, 4624)      : setup scratch (h_w 2700 | r_w 1350 | h_b 150) -> X0 (68x68 ring-2) -> vA (66x68 ring-1)
//  [4624, 9248)   : X1 (68x68 ring-2)  -> reused as vB (66x68 ring-1)
//  [9248, 13736)  : R  (66x68 ring-1)  -- intact through phase 5
//  [13736, 14178) : weights: w2(162) rhb(+162) qw(+171,180) qb(+351,10) fcw(+361,80) rb(+441)
#define SR_OFF 9248
#define SW_OFF 13736
#define LDS_TOT 14178

__device__ __forceinline__ void vi_step(const float* __restrict__ cur, float* __restrict__ nxt,
                                        int row, int col0,
                                        const float (&qr)[10][8], const float (&qwv)[10][9]) {
    float nb[3][12];
#pragma unroll
    for (int dy = 0; dy < 3; ++dy) {
#pragma unroll
        for (int j = 0; j < 3; ++j) {
            float4 v = *(const float4*)&cur[(row + dy) * 68 + col0 + 4 * j];
            nb[dy][4 * j + 0] = v.x; nb[dy][4 * j + 1] = v.y;
            nb[dy][4 * j + 2] = v.z; nb[dy][4 * j + 3] = v.w;
        }
    }
    float vmax[8];
#pragma unroll
    for (int c = 0; c < 10; ++c) {
#pragma unroll
        for (int p = 0; p < 8; ++p) {
            float acc = qr[c][p];
#pragma unroll
            for (int ky = 0; ky < 3; ++ky)
#pragma unroll
                for (int kx = 0; kx < 3; ++kx)
                    acc = fmaf(qwv[c][ky * 3 + kx], nb[ky][p + kx], acc);
            vmax[p] = (c == 0) ? acc : fmaxf(vmax[p], acc);
        }
    }
#pragma unroll
    for (int p = 0; p < 8; ++p)
        nxt[(row + 1) * 68 + col0 + 1 + p] = vmax[p];
}

// 512 threads = 8 waves = 2 waves/SIMD at 1 block/CU -> budget 256 VGPRs.
// CRITICAL: qr/qwv must only ever be indexed with compile-time constants
// (rule: one runtime index forces the whole array into scratch; that was the
// 20.5 MB WRITE_SIZE + 80 scratch reloads/step in the previous version).
__launch_bounds__(512, 2)
__global__ void vin_main(const float* __restrict__ x,
                         const int* __restrict__ pos_x, const int* __restrict__ pos_y,
                         const float* __restrict__ h_w, const float* __restrict__ h_b,
                         const float* __restrict__ r_w, const float* __restrict__ r_b,
                         const float* __restrict__ q_w, const float* __restrict__ q_b,
                         const float* __restrict__ fc_w, float* __restrict__ out) {
    __shared__ __align__(16) float S[LDS_TOT];
    const int tid = threadIdx.x;
    const int b = blockIdx.x;
    const int row = tid >> 3;          // 0..63
    const int col0 = (tid & 7) << 3;   // 0,8,..,56
    float* SW = S + SW_OFF;

    // phase A: stage raw weights into scratch (region later zeroed for X0/X1),
    //          and loop weights into SW[171..442)
    for (int i = tid; i < 2700; i += 512) S[i] = h_w[i];
    for (int i = tid; i < 1350; i += 512) S[2700 + i] = r_w[i];
    if (tid < 150) S[4050 + tid] = h_b[tid];
    for (int i = tid; i < 180; i += 512) SW[171 + i] = q_w[i];
    if (tid < 10) SW[351 + tid] = q_b[tid];
    for (int i = tid; i < 80; i += 512) SW[361 + i] = fc_w[i];
    if (tid == 0) SW[441] = r_b[0];
    __syncthreads();

    // phase B: composite 2-stage conv weights w2[2][9][9] + rhb[9] (fmaf order
    // identical to the original vin_setup kernel -> bitwise-identical results)
    if (tid < 162) {
        int i = tid / 81, rem = tid % 81, dq = rem / 9, ds = rem % 9;
        const float* rw = S + 2700;
        float s = 0.f;
        for (int m = 0; m < 150; ++m)
            s = fmaf(rw[m * 9 + dq], S[(m * 2 + i) * 9 + ds], s);
        SW[tid] = s;
    } else if (tid < 171) {
        int dq = tid - 162;
        const float* rw = S + 2700;
        const float* hb = S + 4050;
        float s = 0.f;
        for (int m = 0; m < 150; ++m)
            s = fmaf(rw[m * 9 + dq], hb[m], s);
        SW[tid] = s;
    }
    __syncthreads();

    // phase 0: zero X0/X1/R regions (13736 = 4*3434 floats)
    float4 z4 = make_float4(0.f, 0.f, 0.f, 0.f);
    for (int i = tid; i < 3434; i += 512) ((float4*)S)[i] = z4;
    __syncthreads();

    // phase 1: stage x[b] into X0/X1 interior (ring-2 stays zero)
    {
        const float4* xg = (const float4*)(x + (size_t)b * 8192);
        for (int i = tid; i < 2048; i += 512) {
            float4 v = xg[i];
            int ch = i >> 10, rem = i & 1023;
            int y = rem >> 4, xc = (rem & 15) << 2;
            float* dst = S + ch * 4624 + (y + 2) * 68 + xc + 2;
            dst[0] = v.x; dst[1] = v.y; dst[2] = v.z; dst[3] = v.w;
        }
    }
    __syncthreads();

    // phase 2: r = composite 2-stage conv via w2/rhb, exact border clipping on q
    {
        float xb0[5][12], xb1[5][12];
        const float* X0 = S;
        const float* X1 = S + 4624;
#pragma unroll
        for (int dy = 0; dy < 5; ++dy) {
#pragma unroll
            for (int j = 0; j < 3; ++j) {
                float4 a = *(const float4*)&X0[(row + dy) * 68 + col0 + 4 * j];
                xb0[dy][4 * j + 0] = a.x; xb0[dy][4 * j + 1] = a.y;
                xb0[dy][4 * j + 2] = a.z; xb0[dy][4 * j + 3] = a.w;
                float4 c = *(const float4*)&X1[(row + dy) * 68 + col0 + 4 * j];
                xb1[dy][4 * j + 0] = c.x; xb1[dy][4 * j + 1] = c.y;
                xb1[dy][4 * j + 2] = c.z; xb1[dy][4 * j + 3] = c.w;
            }
        }
        float racc[8];
        float rbv = SW[441];
#pragma unroll
        for (int p = 0; p < 8; ++p) racc[p] = rbv;
#pragma unroll
        for (int dqy = 0; dqy < 3; ++dqy) {
            bool rowok = (row + dqy >= 1) && (row + dqy <= 64);
#pragma unroll
            for (int dqx = 0; dqx < 3; ++dqx) {
                int dq = dqy * 3 + dqx;
                float rh = SW[162 + dq];
                float w20[9], w21[9];
#pragma unroll
                for (int ds = 0; ds < 9; ++ds) {
                    w20[ds] = SW[dq * 9 + ds];
                    w21[ds] = SW[81 + dq * 9 + ds];
                }
#pragma unroll
                for (int p = 0; p < 8; ++p) {
                    float t = rh;
#pragma unroll
                    for (int dsy = 0; dsy < 3; ++dsy)
#pragma unroll
                        for (int dsx = 0; dsx < 3; ++dsx) {
                            int ds = dsy * 3 + dsx;
                            t = fmaf(w20[ds], xb0[dqy + dsy][p + dqx + dsx], t);
                            t = fmaf(w21[ds], xb1[dqy + dsy][p + dqx + dsx], t);
                        }
                    int qx = col0 + p + dqx - 1;
                    bool ok = rowok && (qx >= 0) && (qx < 64);
                    racc[p] += ok ? t : 0.f;
                }
            }
        }
        float* SR = S + SR_OFF;
#pragma unroll
        for (int p = 0; p < 8; ++p)
            SR[(row + 1) * 68 + col0 + 1 + p] = racc[p];
    }
    __syncthreads();

    // phase 3: qr = conv(r, q_w[:,0]) + q_b into registers; load loop weights; re-zero v buffers
    float qr[10][8];
    float qwv[10][9];
    {
        float rnb[3][12];
        const float* SR = S + SR_OFF;
#pragma unroll
        for (int dy = 0; dy < 3; ++dy) {
#pragma unroll
            for (int j = 0; j < 3; ++j) {
                float4 v = *(const float4*)&SR[(row + dy) * 68 + col0 + 4 * j];
                rnb[dy][4 * j + 0] = v.x; rnb[dy][4 * j + 1] = v.y;
                rnb[dy][4 * j + 2] = v.z; rnb[dy][4 * j + 3] = v.w;
            }
        }
#pragma unroll
        for (int c = 0; c < 10; ++c) {
            float qbc = SW[351 + c];
            float w[9];
#pragma unroll
            for (int j = 0; j < 9; ++j) w[j] = SW[171 + c * 18 + j];
#pragma unroll
            for (int p = 0; p < 8; ++p) {
                float acc = qbc;
#pragma unroll
                for (int ky = 0; ky < 3; ++ky)
#pragma unroll
                    for (int kx = 0; kx < 3; ++kx)
                        acc = fmaf(w[ky * 3 + kx], rnb[ky][p + kx], acc);
                qr[c][p] = acc;
            }
        }
#pragma unroll
        for (int c = 0; c < 10; ++c)
#pragma unroll
            for (int j = 0; j < 9; ++j) qwv[c][j] = SW[171 + c * 18 + 9 + j];
        // re-zero vA/vB region (was X0/X1 with x data); v0 = 0, rings stay 0 forever
        for (int i = tid; i < 2312; i += 512) ((float4*)S)[i] = z4;
    }
    __syncthreads();

    // phase 4: 50 VI steps, double-buffered v in LDS (ends with result in vA)
    float* vA = S;
    float* vB = S + 4624;
#pragma unroll 1
    for (int k = 0; k < K_ITERS / 2; ++k) {
        vi_step(vA, vB, row, col0, qr, qwv);
        __syncthreads();
        vi_step(vB, vA, row, col0, qr, qwv);
        __syncthreads();
    }

    // phase 5: final q at (pos_x, pos_y) + FC, by the owning thread.
    // Recompute the r-part of q from SR (still intact) instead of reading
    // qr[c][p] with runtime p -- a runtime index would force the whole qr
    // array into scratch. Same fmaf order as phase 3 -> bitwise identical.
    int pr = pos_x[b], pc = pos_y[b];
    if (row == pr && (pc >> 3) == (tid & 7)) {
        const float* SR = S + SR_OFF;
        float qf[10];
#pragma unroll
        for (int c = 0; c < 10; ++c) {
            float acc = SW[351 + c];
#pragma unroll
            for (int ky = 0; ky < 3; ++ky)
#pragma unroll
                for (int kx = 0; kx < 3; ++kx)
                    acc = fmaf(SW[171 + c * 18 + ky * 3 + kx], SR[(pr + ky) * 68 + pc + kx], acc);
#pragma unroll
            for (int ky = 0; ky < 3; ++ky)
#pragma unroll
                for (int kx = 0; kx < 3; ++kx)
                    acc = fmaf(qwv[c][3 * ky + kx], vA[(pr + ky) * 68 + pc + kx], acc);
            qf[c] = acc;
        }
#pragma unroll
        for (int o = 0; o < 8; ++o) {
            float s = 0.f;
#pragma unroll
            for (int c = 0; c < 10; ++c) s = fmaf(SW[361 + o * 10 + c], qf[c], s);
            out[b * 8 + o] = s;
        }
    }
}

extern "C" void kernel_launch(void* const* d_in, const int* in_sizes, int n_in,
                              void* d_out, int out_size, void* d_ws, size_t ws_size,
                              hipStream_t stream) {
    const float* x     = (const float*)d_in[0];
    const int*   pos_x = (const int*)d_in[1];
    const int*   pos_y = (const int*)d_in[2];
    const float* h_w   = (const float*)d_in[3];
    const float* h_b   = (const float*)d_in[4];
    const float* r_w   = (const float*)d_in[5];
    const float* r_b   = (const float*)d_in[6];
    const float* q_w   = (const float*)d_in[7];
    const float* q_b   = (const float*)d_in[8];
    const float* fc_w  = (const float*)d_in[9];
    float* out = (float*)d_out;

    vin_main<<<128, 512, 0, stream>>>(x, pos_x, pos_y, h_w, h_b, r_w, r_b, q_w, q_b, fc_w, out);
}